// Round 11
// baseline (598.441 us; speedup 1.0000x reference)
//
#include <hip/hip_runtime.h>
#include <math.h>

#define TPB 320           // 1 compute wave + 4 builder waves
#define LDM 72            // bf16 row stride (144 B): 16B-aligned b128
#define SLOTS 4608        // 64*72 shorts = one 64x64 bf16 matrix slot

// ---------------------------------------------------------------------------
// N=129, B=128, D=64, NOUT=65, NIN=64, NMID=63
// x: (129,128,2) fp32 | mps_input mi2[n*4096+l*64+r]=(t0,t1) | mps_output
// mo4[n*4096+l*64+r]=(00,01,10,11).  out: 129 fp32 (128 per-b + lnrm).
//
// R11 = R10 with the stt() arity fix. SINGLE-WAVE congruence: wave 0 computes
// the full 64x64 congruence S' = sum_g G^T S G per site (S A-frags read once,
// U through dbuf LDS slot, in-wave amax butterfly); waves 1-4 build next-site
// generators into parity-buffered slots -> ONE barrier per site.
// Storage (verified R9): stor[c*LDM+r] = M[r][c]; same ldf serves A/B roles.
// Slots: 0=S | 1,14=U dbuf | Gi(p,g)=2+p*2+g | Go(p,g)=6+p*4+g.
// ---------------------------------------------------------------------------

typedef __attribute__((ext_vector_type(8))) short bf16x8;
typedef __attribute__((ext_vector_type(4))) float f32x4;
typedef unsigned short US;

__device__ __forceinline__ US f2b(float f) {
    union { float f; unsigned u; } v; v.f = f;
    return (US)((v.u + 0x7FFFu + ((v.u >> 16) & 1u)) >> 16);
}
__device__ __forceinline__ float bf2f(US h) {
    union { unsigned u; float f; } v; v.u = ((unsigned)h) << 16; return v.f;
}

struct Frag { bf16x8 lo, hi; };

__device__ __forceinline__ Frag ldf(const US* buf, int row0, int lane) {
    const US* p = buf + (row0 + (lane & 15)) * LDM + ((lane >> 4) << 3);
    Frag f; f.lo = *(const bf16x8*)p; f.hi = *(const bf16x8*)(p + 32); return f;
}
__device__ __forceinline__ f32x4 mm(const Frag& a, const Frag& b, f32x4 c) {
    c = __builtin_amdgcn_mfma_f32_16x16x32_bf16(a.lo, b.lo, c, 0, 0, 0);
    c = __builtin_amdgcn_mfma_f32_16x16x32_bf16(a.hi, b.hi, c, 0, 0, 0);
    return c;
}
// 16x16 C-tile -> transposed-bf16 store (C layout: col=lane&15, row=quad*4+reg)
__device__ __forceinline__ void stt(US* dst, f32x4 d, float s,
                                    int col0, int row0, int lane) {
    ushort4 wv;
    wv.x = f2b(d.x * s); wv.y = f2b(d.y * s);
    wv.z = f2b(d.z * s); wv.w = f2b(d.w * s);
    *(ushort4*)(dst + (col0 + (lane & 15)) * LDM + row0 + ((lane >> 4) << 2)) = wv;
}

// Full 64x64 congruence on one wave: acc = sum_g G_g^T S G_g
template<int NG>
__device__ __forceinline__ void congr_full(US* sm, const US* S, const US* Gb,
                                           f32x4 acc[4][4], int lane) {
    Frag aS[4];
#pragma unroll
    for (int rt = 0; rt < 4; ++rt) aS[rt] = ldf(S, rt * 16, lane);
#pragma unroll
    for (int rt = 0; rt < 4; ++rt)
#pragma unroll
        for (int ct = 0; ct < 4; ++ct) acc[rt][ct] = (f32x4){0.f, 0.f, 0.f, 0.f};
#pragma unroll
    for (int g = 0; g < NG; ++g) {
        const US* G = Gb + g * SLOTS;
        US* U = sm + (1 + 13 * (g & 1)) * SLOTS;   // slots 1 / 14 (dbuf)
#pragma unroll
        for (int ct = 0; ct < 4; ++ct) {           // stage1: U = S*G
            Frag bG = ldf(G, ct * 16, lane);
#pragma unroll
            for (int rt = 0; rt < 4; ++rt) {
                f32x4 d = {0.f, 0.f, 0.f, 0.f};
                d = mm(aS[rt], bG, d);
                stt(U, d, 1.f, ct * 16, rt * 16, lane);
            }
        }
        Frag gA[4];
#pragma unroll
        for (int rt = 0; rt < 4; ++rt) gA[rt] = ldf(G, rt * 16, lane);
#pragma unroll
        for (int ct = 0; ct < 4; ++ct) {           // stage2: acc += G^T U
            Frag bU = ldf(U, ct * 16, lane);
#pragma unroll
            for (int rt = 0; rt < 4; ++rt)
                acc[rt][ct] = mm(gA[rt], bU, acc[rt][ct]);
        }
    }
}

__device__ __forceinline__ float amax16(const f32x4 acc[4][4]) {
    float m = 0.f;
#pragma unroll
    for (int rt = 0; rt < 4; ++rt)
#pragma unroll
        for (int ct = 0; ct < 4; ++ct)
            m = fmaxf(m, fmaxf(fmaxf(fabsf(acc[rt][ct].x), fabsf(acc[rt][ct].y)),
                               fmaxf(fabsf(acc[rt][ct].z), fabsf(acc[rt][ct].w))));
#pragma unroll
    for (int off = 32; off; off >>= 1) m = fmaxf(m, __shfl_xor(m, off, 64));
    return m;   // broadcast to all lanes
}

__device__ __forceinline__ void store16(US* dst, const f32x4 acc[4][4], float s,
                                        int lane) {
#pragma unroll
    for (int rt = 0; rt < 4; ++rt)
#pragma unroll
        for (int ct = 0; ct < 4; ++ct)
            stt(dst, acc[rt][ct], s, ct * 16, rt * 16, lane);
}

__global__ __launch_bounds__(TPB)
void mps_proj_kernel(const float* __restrict__ x,
                     const float* __restrict__ mi,
                     const float* __restrict__ mo,
                     float* __restrict__ out) {
    __shared__ __align__(16) US smem[15 * SLOTS];
#define SL(i) (smem + (i) * SLOTS)
    __shared__ float fsA[256];
    __shared__ float fsr[8];
    __shared__ float fsv[128];

    const int tid  = threadIdx.x;
    const int lane = tid & 63;
    const int w    = tid >> 6;

    const float2* mi2 = (const float2*)mi;
    const float4* mo4 = (const float4*)mo;

    float logsum = 0.f;
    f32x4 acc[4][4];

    if (blockIdx.x < 128) {
        // =================== per-batch MPS scan, b = blockIdx.x ==================
        const int b = blockIdx.x;
        const float xa = x[b * 2 + 0], xb = x[b * 2 + 1];
        if (tid < 64) {
            float4 v = mo4[tid];
            fsA[tid * 2 + 0] = xa * v.x + xb * v.z;
            fsA[tid * 2 + 1] = xa * v.y + xb * v.w;
        }
        __syncthreads();
        float mloc = 0.f;
        for (int pos = tid; pos < 4096; pos += TPB) {
            int u = pos >> 6, d = pos & 63;
            float s = fsA[u * 2] * fsA[d * 2] + fsA[u * 2 + 1] * fsA[d * 2 + 1];
            mloc = fmaxf(mloc, fabsf(s));
        }
#pragma unroll
        for (int off = 32; off; off >>= 1) mloc = fmaxf(mloc, __shfl_down(mloc, off, 64));
        if (lane == 0) fsr[w] = mloc;
        __syncthreads();
        float amax = fsr[0];
#pragma unroll
        for (int i = 1; i < 5; ++i) amax = fmaxf(amax, fsr[i]);
        logsum = logf(amax);
        {
            float inv = 1.f / amax;
            for (int pos = tid; pos < 4096; pos += TPB) {
                int u = pos >> 6, d = pos & 63;
                float s = fsA[u * 2] * fsA[d * 2] + fsA[u * 2 + 1] * fsA[d * 2 + 1];
                SL(0)[u * LDM + d] = f2b(s * inv);
            }
        }
        if (w >= 1) {   // init builders: Ain(0)->Gi(p0), X(1)->Go(p0)
            const int j = w - 1;
            const float x1a = x[256 + b * 2 + 0], x1b = x[256 + b * 2 + 1];
            const float x0a = x[512 + b * 2 + 0], x0b = x[512 + b * 2 + 1];
            const float4* so = mo4 + 4096;
            bf16x8 g0, g1, a0, a1, c0, c1;
#pragma unroll
            for (int t = 0; t < 8; ++t) {
                float2 m0 = mi2[(16 * j + t) * 64 + lane];
                float2 m1 = mi2[(16 * j + 8 + t) * 64 + lane];
                g0[t] = (short)f2b(x1a * m0.x + x1b * m0.y);
                g1[t] = (short)f2b(x1a * m1.x + x1b * m1.y);
                float4 o0 = so[(16 * j + t) * 64 + lane];
                float4 o1 = so[(16 * j + 8 + t) * 64 + lane];
                a0[t] = (short)f2b(x0a * o0.x + x0b * o0.z);
                c0[t] = (short)f2b(x0a * o0.y + x0b * o0.w);
                a1[t] = (short)f2b(x0a * o1.x + x0b * o1.z);
                c1[t] = (short)f2b(x0a * o1.y + x0b * o1.w);
            }
            *(bf16x8*)(SL(2) + lane * LDM + 16 * j) = g0;
            *(bf16x8*)(SL(2) + lane * LDM + 16 * j + 8) = g1;
            *(bf16x8*)(SL(6) + lane * LDM + 16 * j) = a0;
            *(bf16x8*)(SL(6) + lane * LDM + 16 * j + 8) = a1;
            *(bf16x8*)(SL(7) + lane * LDM + 16 * j) = c0;
            *(bf16x8*)(SL(7) + lane * LDM + 16 * j + 8) = c1;
        }
        __syncthreads();

        for (int k = 0; k < 63; ++k) {
            const int p = k & 1, np = 1 - p;
            if (w == 0) {
                congr_full<1>(smem, SL(0), SL(2 + p * 2), acc, lane);   // Ain^T S Ain
                store16(SL(0), acc, 1.f, lane);                          // unscaled mid
                congr_full<2>(smem, SL(0), SL(6 + p * 4), acc, lane);   // sum_t X^T S X
                float m = amax16(acc);
                logsum += logf(m);
                store16(SL(0), acc, 1.f / m, lane);
            } else {
                const int j = w - 1;
                if (k < 62) {
                    const float x1a = x[(2 * k + 3) * 256 + b * 2 + 0];
                    const float x1b = x[(2 * k + 3) * 256 + b * 2 + 1];
                    const float x0a = x[(2 * k + 4) * 256 + b * 2 + 0];
                    const float x0b = x[(2 * k + 4) * 256 + b * 2 + 1];
                    const float2* si = mi2 + (k + 1) * 4096;
                    const float4* so = mo4 + (k + 2) * 4096;
                    bf16x8 g0, g1, a0, a1, c0, c1;
#pragma unroll
                    for (int t = 0; t < 8; ++t) {
                        float2 m0 = si[(16 * j + t) * 64 + lane];
                        float2 m1 = si[(16 * j + 8 + t) * 64 + lane];
                        g0[t] = (short)f2b(x1a * m0.x + x1b * m0.y);
                        g1[t] = (short)f2b(x1a * m1.x + x1b * m1.y);
                        float4 o0 = so[(16 * j + t) * 64 + lane];
                        float4 o1 = so[(16 * j + 8 + t) * 64 + lane];
                        a0[t] = (short)f2b(x0a * o0.x + x0b * o0.z);
                        c0[t] = (short)f2b(x0a * o0.y + x0b * o0.w);
                        a1[t] = (short)f2b(x0a * o1.x + x0b * o1.z);
                        c1[t] = (short)f2b(x0a * o1.y + x0b * o1.w);
                    }
                    *(bf16x8*)(SL(2 + np * 2) + lane * LDM + 16 * j) = g0;
                    *(bf16x8*)(SL(2 + np * 2) + lane * LDM + 16 * j + 8) = g1;
                    *(bf16x8*)(SL(6 + np * 4) + lane * LDM + 16 * j) = a0;
                    *(bf16x8*)(SL(6 + np * 4) + lane * LDM + 16 * j + 8) = a1;
                    *(bf16x8*)(SL(7 + np * 4) + lane * LDM + 16 * j) = c0;
                    *(bf16x8*)(SL(7 + np * 4) + lane * LDM + 16 * j + 8) = c1;
                } else {   // k == 62: only Ain(63) needed (epilogue)
                    const float x1a = x[127 * 256 + b * 2 + 0];
                    const float x1b = x[127 * 256 + b * 2 + 1];
                    const float2* si = mi2 + 63 * 4096;
                    bf16x8 g0, g1;
#pragma unroll
                    for (int t = 0; t < 8; ++t) {
                        float2 m0 = si[(16 * j + t) * 64 + lane];
                        float2 m1 = si[(16 * j + 8 + t) * 64 + lane];
                        g0[t] = (short)f2b(x1a * m0.x + x1b * m0.y);
                        g1[t] = (short)f2b(x1a * m1.x + x1b * m1.y);
                    }
                    *(bf16x8*)(SL(4) + lane * LDM + 16 * j) = g0;
                    *(bf16x8*)(SL(4) + lane * LDM + 16 * j + 8) = g1;
                }
            }
            __syncthreads();
        }

        // ---- last site: out[b] = logsum + log(sum_i v_i^T S v_i) ----
        {
            const float x0a = x[128 * 256 + b * 2 + 0];
            const float x0b = x[128 * 256 + b * 2 + 1];
            if (tid < 64) {
                float4 v = mo4[64 * 4096 + tid * 64];
                fsA[tid * 2 + 0] = x0a * v.x + x0b * v.z;
                fsA[tid * 2 + 1] = x0a * v.y + x0b * v.w;
            }
            __syncthreads();
            if (tid < 128) {        // v[l][i] = sum_r Ain63[l][r] w[r][i]; Ain63 @ SL(4)
                int dd = tid >> 1, ii = tid & 1;
                float s = 0.f;
                for (int r = 0; r < 64; ++r)
                    s += bf2f(SL(4)[r * LDM + dd]) * fsA[r * 2 + ii];
                fsv[tid] = s;
            }
            __syncthreads();
            float part = 0.f;
            for (int pos = tid; pos < 4096; pos += TPB) {
                int dd = pos >> 6, uu = pos & 63;
                part += bf2f(SL(0)[dd * LDM + uu]) *
                        (fsv[dd * 2] * fsv[uu * 2] + fsv[dd * 2 + 1] * fsv[uu * 2 + 1]);
            }
#pragma unroll
            for (int off = 32; off; off >>= 1) part += __shfl_down(part, off, 64);
            if (lane == 0) fsr[w] = part;
            __syncthreads();
            if (tid == 0) {
                float t = 0.f;
#pragma unroll
                for (int i = 0; i < 5; ++i) t += fsr[i];
                out[b] = logsum + logf(t);
            }
        }
    } else {
        // ============================ lnrm scalar chain ==========================
        if (tid < 64) {
            float4 v = mo4[tid];
            fsA[tid * 4 + 0] = v.x; fsA[tid * 4 + 1] = v.y;
            fsA[tid * 4 + 2] = v.z; fsA[tid * 4 + 3] = v.w;
        }
        __syncthreads();
        float mloc = 0.f;
        for (int pos = tid; pos < 4096; pos += TPB) {
            int kk = pos >> 6, ll = pos & 63;
            float s = fsA[kk*4+0]*fsA[ll*4+0] + fsA[kk*4+1]*fsA[ll*4+1] +
                      fsA[kk*4+2]*fsA[ll*4+2] + fsA[kk*4+3]*fsA[ll*4+3];
            mloc = fmaxf(mloc, fabsf(s));
        }
#pragma unroll
        for (int off = 32; off; off >>= 1) mloc = fmaxf(mloc, __shfl_down(mloc, off, 64));
        if (lane == 0) fsr[w] = mloc;
        __syncthreads();
        float amax = fsr[0];
#pragma unroll
        for (int i = 1; i < 5; ++i) amax = fmaxf(amax, fsr[i]);
        logsum = logf(amax);
        {
            float inv = 1.f / amax;
            for (int pos = tid; pos < 4096; pos += TPB) {
                int kk = pos >> 6, ll = pos & 63;
                float s = fsA[kk*4+0]*fsA[ll*4+0] + fsA[kk*4+1]*fsA[ll*4+1] +
                          fsA[kk*4+2]*fsA[ll*4+2] + fsA[kk*4+3]*fsA[ll*4+3];
                SL(0)[kk * LDM + ll] = f2b(s * inv);
            }
        }
        if (w >= 1) {   // init builders: Gi(0)=mi[0] -> SL(2,3); Go(0)=mo[1] -> SL(6..9)
            const int j = w - 1;
            const float4* so = mo4 + 4096;
            bf16x8 g00, g01, g10, g11;
            bf16x8 o[4][2];
#pragma unroll
            for (int t = 0; t < 8; ++t) {
                float2 m0 = mi2[(16 * j + t) * 64 + lane];
                float2 m1 = mi2[(16 * j + 8 + t) * 64 + lane];
                g00[t] = (short)f2b(m0.x); g10[t] = (short)f2b(m0.y);
                g01[t] = (short)f2b(m1.x); g11[t] = (short)f2b(m1.y);
                float4 o0 = so[(16 * j + t) * 64 + lane];
                float4 o1 = so[(16 * j + 8 + t) * 64 + lane];
                o[0][0][t] = (short)f2b(o0.x); o[1][0][t] = (short)f2b(o0.y);
                o[2][0][t] = (short)f2b(o0.z); o[3][0][t] = (short)f2b(o0.w);
                o[0][1][t] = (short)f2b(o1.x); o[1][1][t] = (short)f2b(o1.y);
                o[2][1][t] = (short)f2b(o1.z); o[3][1][t] = (short)f2b(o1.w);
            }
            *(bf16x8*)(SL(2) + lane * LDM + 16 * j) = g00;
            *(bf16x8*)(SL(2) + lane * LDM + 16 * j + 8) = g01;
            *(bf16x8*)(SL(3) + lane * LDM + 16 * j) = g10;
            *(bf16x8*)(SL(3) + lane * LDM + 16 * j + 8) = g11;
#pragma unroll
            for (int c = 0; c < 4; ++c) {
                *(bf16x8*)(SL(6 + c) + lane * LDM + 16 * j) = o[c][0];
                *(bf16x8*)(SL(6 + c) + lane * LDM + 16 * j + 8) = o[c][1];
            }
        }
        __syncthreads();

        for (int n = 0; n < 64; ++n) {
            const int p = n & 1, np = 1 - p;
            if (w == 0) {
                congr_full<2>(smem, SL(0), SL(2 + p * 2), acc, lane);   // contract_in
                float a2 = amax16(acc);
                logsum += logf(a2);
                store16(SL(0), acc, 1.f / a2, lane);
                congr_full<4>(smem, SL(0), SL(6 + p * 4), acc, lane);   // contract_out
                if (n < 63) {
                    float a1 = amax16(acc);
                    logsum += logf(a1);
                    store16(SL(0), acc, 1.f / a1, lane);
                } else {
                    // AlN[0][0]: tile(0,0), lane0, reg x
                    if (lane == 0) out[128] = logsum + logf(acc[0][0].x);
                }
            } else if (n < 63) {
                const int j = w - 1;
                const float2* si = mi2 + (n + 1) * 4096;
                const float4* so = mo4 + (n + 2) * 4096;
                bf16x8 g00, g01, g10, g11;
                bf16x8 o[4][2];
#pragma unroll
                for (int t = 0; t < 8; ++t) {
                    float2 m0 = si[(16 * j + t) * 64 + lane];
                    float2 m1 = si[(16 * j + 8 + t) * 64 + lane];
                    g00[t] = (short)f2b(m0.x); g10[t] = (short)f2b(m0.y);
                    g01[t] = (short)f2b(m1.x); g11[t] = (short)f2b(m1.y);
                    float4 o0 = so[(16 * j + t) * 64 + lane];
                    float4 o1 = so[(16 * j + 8 + t) * 64 + lane];
                    o[0][0][t] = (short)f2b(o0.x); o[1][0][t] = (short)f2b(o0.y);
                    o[2][0][t] = (short)f2b(o0.z); o[3][0][t] = (short)f2b(o0.w);
                    o[0][1][t] = (short)f2b(o1.x); o[1][1][t] = (short)f2b(o1.y);
                    o[2][1][t] = (short)f2b(o1.z); o[3][1][t] = (short)f2b(o1.w);
                }
                *(bf16x8*)(SL(2 + np * 2) + lane * LDM + 16 * j) = g00;
                *(bf16x8*)(SL(2 + np * 2) + lane * LDM + 16 * j + 8) = g01;
                *(bf16x8*)(SL(3 + np * 2) + lane * LDM + 16 * j) = g10;
                *(bf16x8*)(SL(3 + np * 2) + lane * LDM + 16 * j + 8) = g11;
#pragma unroll
                for (int c = 0; c < 4; ++c) {
                    *(bf16x8*)(SL(6 + np * 4 + c) + lane * LDM + 16 * j) = o[c][0];
                    *(bf16x8*)(SL(6 + np * 4 + c) + lane * LDM + 16 * j + 8) = o[c][1];
                }
            }
            __syncthreads();
        }
    }
#undef SL
}

extern "C" void kernel_launch(void* const* d_in, const int* in_sizes, int n_in,
                              void* d_out, int out_size, void* d_ws, size_t ws_size,
                              hipStream_t stream) {
    (void)in_sizes; (void)n_in; (void)d_ws; (void)ws_size; (void)out_size;
    const float* x  = (const float*)d_in[0];
    const float* mi = (const float*)d_in[1];
    const float* mo = (const float*)d_in[2];
    float* out = (float*)d_out;
    hipLaunchKernelGGL(mps_proj_kernel, dim3(129), dim3(TPB), 0, stream,
                       x, mi, mo, out);
}

// Round 12
// 261.543 us; speedup vs baseline: 2.2881x; 2.2881x over previous
//
#include <hip/hip_runtime.h>
#include <math.h>

#define TPB 512
#define LDM 72            // bf16 row stride (144 B): 16B-aligned b128
#define SLOTS 4608        // 64*72 shorts = one 64x64 bf16 matrix slot

// ---------------------------------------------------------------------------
// N=129, B=128, D=64, NOUT=65, NIN=64, NMID=63
// x: (129,128,2) fp32 | mps_input mi2[n*4096+l*64+r]=(t0,t1) | mps_output
// mo4[n*4096+l*64+r]=(00,01,10,11).  out: 129 fp32 (128 per-b + lnrm).
//
// R12 = R9 (4 congr waves own 16-col strips + 4 builder waves, deferred amax,
// 2 barriers/site) with a software-pipelined congruence: all B-strips and S
// A-frags loaded up front, stage1 for ALL gens before stage2 (in-order LDS
// queue overlaps g0's U-read with g1..3's stores), and the wave's bG strip
// register-reused as its stage2 A-frag (rt==CT, compile-time via template).
// Storage (verified): stor[c*LDM+r] = M[r][c]; S symmetric -> row==col major.
// Slots: 0=S, 1=S', 2-3=Gi, 4-7=Go, 8-11=U scratch (one per congr wave).
// ---------------------------------------------------------------------------

typedef __attribute__((ext_vector_type(8))) short bf16x8;
typedef __attribute__((ext_vector_type(4))) float f32x4;
typedef unsigned short US;

__device__ __forceinline__ US f2b(float f) {
    union { float f; unsigned u; } v; v.f = f;
    return (US)((v.u + 0x7FFFu + ((v.u >> 16) & 1u)) >> 16);
}
__device__ __forceinline__ float bf2f(US h) {
    union { unsigned u; float f; } v; v.u = ((unsigned)h) << 16; return v.f;
}

struct Frag { bf16x8 lo, hi; };

// fragment for 16 storage-rows starting row0, K=64 in 2 halves
__device__ __forceinline__ Frag ldf(const US* buf, int row0, int lane) {
    const US* p = buf + (row0 + (lane & 15)) * LDM + ((lane >> 4) << 3);
    Frag f; f.lo = *(const bf16x8*)p; f.hi = *(const bf16x8*)(p + 32); return f;
}
__device__ __forceinline__ f32x4 mm(const Frag& a, const Frag& b, f32x4 c) {
    c = __builtin_amdgcn_mfma_f32_16x16x32_bf16(a.lo, b.lo, c, 0, 0, 0);
    c = __builtin_amdgcn_mfma_f32_16x16x32_bf16(a.hi, b.hi, c, 0, 0, 0);
    return c;
}
// write 16x16 C-tile transposed-bf16 (C layout: col=lane&15, row=quad*4+reg)
__device__ __forceinline__ void stt(US* dst, f32x4 d, float s,
                                    int col0, int row0, int lane) {
    ushort4 wv;
    wv.x = f2b(d.x * s); wv.y = f2b(d.y * s);
    wv.z = f2b(d.z * s); wv.w = f2b(d.w * s);
    *(ushort4*)(dst + (col0 + (lane & 15)) * LDM + row0 + ((lane >> 4) << 2)) = wv;
}

// Pipelined congruence for strip CT: acc = sum_g G_g^T S G_g (cols CT*16..+16)
template<int NG, int CT>
__device__ __forceinline__ void congr16(US* sm, int sSlot, int gSlot, US* Uw,
                                        f32x4 acc[4], int lane) {
    const int C0 = CT * 16;
    const US* S = sm + sSlot * SLOTS;
    Frag aS[4];
#pragma unroll
    for (int rt = 0; rt < 4; ++rt) aS[rt] = ldf(S, rt * 16, lane);
    Frag bG[NG];
#pragma unroll
    for (int g = 0; g < NG; ++g) bG[g] = ldf(sm + (gSlot + g) * SLOTS, C0, lane);
    // stage1 for ALL gens: U_g[:, strip] = S * G_g
#pragma unroll
    for (int g = 0; g < NG; ++g) {
        US* Ug = Uw + g * (16 * LDM);
#pragma unroll
        for (int rt = 0; rt < 4; ++rt) {
            f32x4 d = {0.f, 0.f, 0.f, 0.f};
            d = mm(aS[rt], bG[g], d);
            stt(Ug, d, 1.f, 0, rt * 16, lane);
        }
    }
#pragma unroll
    for (int rt = 0; rt < 4; ++rt) acc[rt] = (f32x4){0.f, 0.f, 0.f, 0.f};
    // stage2: acc += G_g^T U_g  (bG reused as the rt==CT A-frag)
#pragma unroll
    for (int g = 0; g < NG; ++g) {
        const US* G = sm + (gSlot + g) * SLOTS;
        Frag bU = ldf(Uw + g * (16 * LDM), 0, lane);
#pragma unroll
        for (int rt = 0; rt < 4; ++rt) {
            if (rt == CT) {
                acc[rt] = mm(bG[g], bU, acc[rt]);
            } else {
                Frag ga = ldf(G, rt * 16, lane);
                acc[rt] = mm(ga, bU, acc[rt]);
            }
        }
    }
}

template<int NG>
__device__ __forceinline__ void congrD(US* sm, int sSlot, int gSlot, US* Uw,
                                       f32x4 acc[4], int ct, int lane) {
    switch (ct) {
        case 0:  congr16<NG, 0>(sm, sSlot, gSlot, Uw, acc, lane); break;
        case 1:  congr16<NG, 1>(sm, sSlot, gSlot, Uw, acc, lane); break;
        case 2:  congr16<NG, 2>(sm, sSlot, gSlot, Uw, acc, lane); break;
        default: congr16<NG, 3>(sm, sSlot, gSlot, Uw, acc, lane); break;
    }
}

__device__ __forceinline__ void stacc16(US* Sb, const f32x4 acc[4], float s,
                                        int C0, int lane) {
#pragma unroll
    for (int rt = 0; rt < 4; ++rt) stt(Sb, acc[rt], s, C0, rt * 16, lane);
}

// scaled store + wave-max of stored values
__device__ __forceinline__ float stmax16(US* Sb, const f32x4 acc[4], float s,
                                         int C0, int lane) {
    float m = 0.f;
#pragma unroll
    for (int rt = 0; rt < 4; ++rt) {
        float vx = acc[rt].x * s, vy = acc[rt].y * s;
        float vz = acc[rt].z * s, vw = acc[rt].w * s;
        m = fmaxf(m, fmaxf(fmaxf(fabsf(vx), fabsf(vy)),
                           fmaxf(fabsf(vz), fabsf(vw))));
        ushort4 wv; wv.x = f2b(vx); wv.y = f2b(vy); wv.z = f2b(vz); wv.w = f2b(vw);
        *(ushort4*)(Sb + (C0 + (lane & 15)) * LDM + rt * 16 + ((lane >> 4) << 2)) = wv;
    }
#pragma unroll
    for (int off = 32; off; off >>= 1) m = fmaxf(m, __shfl_down(m, off, 64));
    return m;
}

__global__ __launch_bounds__(TPB)
void mps_proj_kernel(const float* __restrict__ x,
                     const float* __restrict__ mi,
                     const float* __restrict__ mo,
                     float* __restrict__ out) {
    __shared__ __align__(16) US smem[12 * SLOTS];
#define SL(i) (smem + (i) * SLOTS)
    __shared__ float fsA[256];
    __shared__ float fsp[8];
    __shared__ float fsrA[2][4];
    __shared__ float fsrB[2][4];
    __shared__ float fsv[128];

    const int tid  = threadIdx.x;
    const int lane = tid & 63;
    const int w    = tid >> 6;
    const int C0   = (w & 3) * 16;                 // congr strip (w<4)
    US* const Uw   = smem + (8 + (w & 3)) * SLOTS; // per-congr-wave U scratch

    const float2* mi2 = (const float2*)mi;
    const float4* mo4 = (const float4*)mo;

    float logsum = 0.f;
    f32x4 acc[4];

    if (blockIdx.x < 128) {
        // =================== per-batch MPS scan, b = blockIdx.x ==================
        const int b = blockIdx.x;
        const float xa = x[b * 2 + 0], xb = x[b * 2 + 1];
        if (tid < 64) {
            float4 v = mo4[tid];
            fsA[tid * 2 + 0] = xa * v.x + xb * v.z;
            fsA[tid * 2 + 1] = xa * v.y + xb * v.w;
        }
        __syncthreads();
        float vals[8]; float mloc = 0.f;
#pragma unroll
        for (int j = 0; j < 8; ++j) {
            int pos = tid + j * TPB; int u = pos >> 6, d = pos & 63;
            float s = fsA[u * 2] * fsA[d * 2] + fsA[u * 2 + 1] * fsA[d * 2 + 1];
            vals[j] = s; mloc = fmaxf(mloc, fabsf(s));
        }
#pragma unroll
        for (int off = 32; off; off >>= 1) mloc = fmaxf(mloc, __shfl_down(mloc, off, 64));
        if (lane == 0) fsp[w] = mloc;
        __syncthreads();
        float amax = fsp[0];
#pragma unroll
        for (int i = 1; i < 8; ++i) amax = fmaxf(amax, fsp[i]);
        logsum = logf(amax);
        {
            float inv = 1.f / amax;
#pragma unroll
            for (int j = 0; j < 8; ++j) {
                int pos = tid + j * TPB;
                SL(0)[(pos >> 6) * LDM + (pos & 63)] = f2b(vals[j] * inv);
            }
        }
        if (w >= 4) {   // build Gi = Ain(0) into slot 2
            const int j = w - 4;
            const float x1a = x[256 + b * 2 + 0], x1b = x[256 + b * 2 + 1];
            bf16x8 g0, g1;
#pragma unroll
            for (int t = 0; t < 8; ++t) {
                float2 m0 = mi2[(16 * j + t) * 64 + lane];
                float2 m1 = mi2[(16 * j + 8 + t) * 64 + lane];
                g0[t] = (short)f2b(x1a * m0.x + x1b * m0.y);
                g1[t] = (short)f2b(x1a * m1.x + x1b * m1.y);
            }
            *(bf16x8*)(SL(2) + lane * LDM + 16 * j) = g0;
            *(bf16x8*)(SL(2) + lane * LDM + 16 * j + 8) = g1;
        }
        if (tid < 4) fsrB[1][tid] = 1.f;   // deferred-scale init (S normalized)
        __syncthreads();

        for (int k = 0; k < 63; ++k) {
            // Phase A: Smid(slot1) = Ain^T S Ain, UNSCALED || build X0,X1(k+1)
            if (w < 4) {
                congrD<1>(smem, 0, 2, Uw, acc, w & 3, lane);
                stacc16(SL(1), acc, 1.f, C0, lane);
            } else {
                const int j = w - 4;
                const float x0a = x[(2 * k + 2) * 256 + b * 2 + 0];
                const float x0b = x[(2 * k + 2) * 256 + b * 2 + 1];
                const float4* so = mo4 + (k + 1) * 4096;
                bf16x8 a0, a1, c0, c1;
#pragma unroll
                for (int t = 0; t < 8; ++t) {
                    float4 m0 = so[(16 * j + t) * 64 + lane];
                    float4 m1 = so[(16 * j + 8 + t) * 64 + lane];
                    a0[t] = (short)f2b(x0a * m0.x + x0b * m0.z);
                    c0[t] = (short)f2b(x0a * m0.y + x0b * m0.w);
                    a1[t] = (short)f2b(x0a * m1.x + x0b * m1.z);
                    c1[t] = (short)f2b(x0a * m1.y + x0b * m1.w);
                }
                *(bf16x8*)(SL(4) + lane * LDM + 16 * j) = a0;
                *(bf16x8*)(SL(4) + lane * LDM + 16 * j + 8) = a1;
                *(bf16x8*)(SL(5) + lane * LDM + 16 * j) = c0;
                *(bf16x8*)(SL(5) + lane * LDM + 16 * j + 8) = c1;
            }
            __syncthreads();
            // Phase B: S(slot0) = (sum_t X_t^T Smid X_t)/a_prev || build Ain(k+1)
            if (w < 4) {
                float a = fmaxf(fmaxf(fsrB[(k + 1) & 1][0], fsrB[(k + 1) & 1][1]),
                                fmaxf(fsrB[(k + 1) & 1][2], fsrB[(k + 1) & 1][3]));
                logsum += logf(a);
                congrD<2>(smem, 1, 4, Uw, acc, w & 3, lane);
                float m = stmax16(SL(0), acc, 1.f / a, C0, lane);
                if (lane == 0) fsrB[k & 1][w] = m;
            } else {
                const int j = w - 4;
                const float x1a = x[(2 * k + 3) * 256 + b * 2 + 0];
                const float x1b = x[(2 * k + 3) * 256 + b * 2 + 1];
                const float2* si = mi2 + (k + 1) * 4096;
                bf16x8 g0, g1;
#pragma unroll
                for (int t = 0; t < 8; ++t) {
                    float2 m0 = si[(16 * j + t) * 64 + lane];
                    float2 m1 = si[(16 * j + 8 + t) * 64 + lane];
                    g0[t] = (short)f2b(x1a * m0.x + x1b * m0.y);
                    g1[t] = (short)f2b(x1a * m1.x + x1b * m1.y);
                }
                *(bf16x8*)(SL(2) + lane * LDM + 16 * j) = g0;
                *(bf16x8*)(SL(2) + lane * LDM + 16 * j + 8) = g1;
            }
            __syncthreads();
        }

        // ---- last site: out[b] = logsum + log(sum_i v_i^T S v_i) ----
        {
            const float x0a = x[128 * 256 + b * 2 + 0];
            const float x0b = x[128 * 256 + b * 2 + 1];
            if (tid < 64) {
                float4 v = mo4[64 * 4096 + tid * 64];
                fsA[tid * 2 + 0] = x0a * v.x + x0b * v.z;
                fsA[tid * 2 + 1] = x0a * v.y + x0b * v.w;
            }
            __syncthreads();
            if (tid < 128) {        // v[l][i] = sum_r Ain63[l][r] w[r][i]
                int dd = tid >> 1, ii = tid & 1;
                float s = 0.f;
                for (int r = 0; r < 64; ++r)
                    s += bf2f(SL(2)[r * LDM + dd]) * fsA[r * 2 + ii];
                fsv[tid] = s;
            }
            __syncthreads();
            float part = 0.f;
#pragma unroll
            for (int j = 0; j < 8; ++j) {
                int pos = tid + j * TPB; int dd = pos >> 6, uu = pos & 63;
                part += bf2f(SL(0)[dd * LDM + uu]) *
                        (fsv[dd * 2] * fsv[uu * 2] + fsv[dd * 2 + 1] * fsv[uu * 2 + 1]);
            }
#pragma unroll
            for (int off = 32; off; off >>= 1) part += __shfl_down(part, off, 64);
            if (lane == 0) fsp[w] = part;
            __syncthreads();
            if (tid == 0) {
                float t = 0.f;
#pragma unroll
                for (int i = 0; i < 8; ++i) t += fsp[i];
                out[b] = logsum + logf(t);
            }
        }
    } else {
        // ============================ lnrm scalar chain ==========================
        if (tid < 64) {
            float4 v = mo4[tid];
            fsA[tid * 4 + 0] = v.x; fsA[tid * 4 + 1] = v.y;
            fsA[tid * 4 + 2] = v.z; fsA[tid * 4 + 3] = v.w;
        }
        __syncthreads();
        float vals[8]; float mloc = 0.f;
#pragma unroll
        for (int j = 0; j < 8; ++j) {
            int pos = tid + j * TPB; int kk = pos >> 6, ll = pos & 63;
            float s = fsA[kk*4+0]*fsA[ll*4+0] + fsA[kk*4+1]*fsA[ll*4+1] +
                      fsA[kk*4+2]*fsA[ll*4+2] + fsA[kk*4+3]*fsA[ll*4+3];
            vals[j] = s; mloc = fmaxf(mloc, fabsf(s));
        }
#pragma unroll
        for (int off = 32; off; off >>= 1) mloc = fmaxf(mloc, __shfl_down(mloc, off, 64));
        if (lane == 0) fsp[w] = mloc;
        __syncthreads();
        float amax = fsp[0];
#pragma unroll
        for (int i = 1; i < 8; ++i) amax = fmaxf(amax, fsp[i]);
        logsum = logf(amax);
        {
            float inv = 1.f / amax;
#pragma unroll
            for (int j = 0; j < 8; ++j) {
                int pos = tid + j * TPB;
                SL(0)[(pos >> 6) * LDM + (pos & 63)] = f2b(vals[j] * inv);
            }
        }
        if (w >= 4) {   // build Gi0,Gi1 from mi[0] -> slots 2,3
            const int j = w - 4;
            bf16x8 g00, g01, g10, g11;
#pragma unroll
            for (int t = 0; t < 8; ++t) {
                float2 m0 = mi2[(16 * j + t) * 64 + lane];
                float2 m1 = mi2[(16 * j + 8 + t) * 64 + lane];
                g00[t] = (short)f2b(m0.x); g10[t] = (short)f2b(m0.y);
                g01[t] = (short)f2b(m1.x); g11[t] = (short)f2b(m1.y);
            }
            *(bf16x8*)(SL(2) + lane * LDM + 16 * j) = g00;
            *(bf16x8*)(SL(2) + lane * LDM + 16 * j + 8) = g01;
            *(bf16x8*)(SL(3) + lane * LDM + 16 * j) = g10;
            *(bf16x8*)(SL(3) + lane * LDM + 16 * j + 8) = g11;
        }
        if (tid < 4) fsrB[1][tid] = 1.f;
        __syncthreads();

        for (int n = 0; n < 64; ++n) {
            // Phase A: S'(slot1) = (sum_t Mi_t^T S Mi_t)/aB || build Go from mo[n+1]
            if (w < 4) {
                float aB = fmaxf(fmaxf(fsrB[(n + 1) & 1][0], fsrB[(n + 1) & 1][1]),
                                 fmaxf(fsrB[(n + 1) & 1][2], fsrB[(n + 1) & 1][3]));
                logsum += logf(aB);
                congrD<2>(smem, 0, 2, Uw, acc, w & 3, lane);
                float m = stmax16(SL(1), acc, 1.f / aB, C0, lane);
                if (lane == 0) fsrA[n & 1][w] = m;
            } else {
                const int j = w - 4;
                const float4* so = mo4 + (n + 1) * 4096;
                bf16x8 g[4][2];
#pragma unroll
                for (int t = 0; t < 8; ++t) {
                    float4 m0 = so[(16 * j + t) * 64 + lane];
                    float4 m1 = so[(16 * j + 8 + t) * 64 + lane];
                    g[0][0][t] = (short)f2b(m0.x); g[1][0][t] = (short)f2b(m0.y);
                    g[2][0][t] = (short)f2b(m0.z); g[3][0][t] = (short)f2b(m0.w);
                    g[0][1][t] = (short)f2b(m1.x); g[1][1][t] = (short)f2b(m1.y);
                    g[2][1][t] = (short)f2b(m1.z); g[3][1][t] = (short)f2b(m1.w);
                }
#pragma unroll
                for (int c = 0; c < 4; ++c) {
                    *(bf16x8*)(SL(4 + c) + lane * LDM + 16 * j) = g[c][0];
                    *(bf16x8*)(SL(4 + c) + lane * LDM + 16 * j + 8) = g[c][1];
                }
            }
            __syncthreads();
            // Phase B: S(slot0) = (sum_c Mo_c^T S' Mo_c)/aA || build Gi(n+1)
            if (w < 4) {
                float aA = fmaxf(fmaxf(fsrA[n & 1][0], fsrA[n & 1][1]),
                                 fmaxf(fsrA[n & 1][2], fsrA[n & 1][3]));
                logsum += logf(aA);
                congrD<4>(smem, 1, 4, Uw, acc, w & 3, lane);
                float m = stmax16(SL(0), acc, 1.f / aA, C0, lane);
                if (lane == 0) fsrB[n & 1][w] = m;
            } else if (n < 63) {
                const int j = w - 4;
                const float2* si = mi2 + (n + 1) * 4096;
                bf16x8 g00, g01, g10, g11;
#pragma unroll
                for (int t = 0; t < 8; ++t) {
                    float2 m0 = si[(16 * j + t) * 64 + lane];
                    float2 m1 = si[(16 * j + 8 + t) * 64 + lane];
                    g00[t] = (short)f2b(m0.x); g10[t] = (short)f2b(m0.y);
                    g01[t] = (short)f2b(m1.x); g11[t] = (short)f2b(m1.y);
                }
                *(bf16x8*)(SL(2) + lane * LDM + 16 * j) = g00;
                *(bf16x8*)(SL(2) + lane * LDM + 16 * j + 8) = g01;
                *(bf16x8*)(SL(3) + lane * LDM + 16 * j) = g10;
                *(bf16x8*)(SL(3) + lane * LDM + 16 * j + 8) = g11;
            }
            __syncthreads();
        }
        if (tid == 0) out[128] = logsum + logf(bf2f(SL(0)[0]));
    }
#undef SL
}

extern "C" void kernel_launch(void* const* d_in, const int* in_sizes, int n_in,
                              void* d_out, int out_size, void* d_ws, size_t ws_size,
                              hipStream_t stream) {
    (void)in_sizes; (void)n_in; (void)d_ws; (void)ws_size; (void)out_size;
    const float* x  = (const float*)d_in[0];
    const float* mi = (const float*)d_in[1];
    const float* mo = (const float*)d_in[2];
    float* out = (float*)d_out;
    hipLaunchKernelGGL(mps_proj_kernel, dim3(129), dim3(TPB), 0, stream,
                       x, mi, mo, out);
}

// Round 13
// 260.540 us; speedup vs baseline: 2.2969x; 1.0038x over previous
//
#include <hip/hip_runtime.h>
#include <math.h>

#define TPB 512
#define LDM 72            // bf16 row stride (144 B): 16B-aligned b128
#define SLOTS 4608        // 64*72 shorts = one 64x64 bf16 matrix slot

// ---------------------------------------------------------------------------
// N=129, B=128, D=64, NOUT=65, NIN=64, NMID=63
// x: (129,128,2) fp32 | mps_input mi2[n*4096+l*64+r]=(t0,t1) | mps_output
// mo4[n*4096+l*64+r]=(00,01,10,11).  out: 129 fp32 (128 per-b + lnrm).
//
// R13 = R12 + bank-conflict-free chunk-XOR swizzle: logical 8-elem chunk c of
// storage row r lives at physical chunk c ^ ((r>>3)&1). LDM=72 advances banks
// by 4/row (period 8), so rows i,i+8 of a 16-row fragment aliased -> 2-way
// conflict on every ds_read_b128 (SQ_LDS_BANK_CONFLICT=8.6e6 ~ 13% of cycles).
// The XOR breaks the period-8 aliasing; reads/writes land on the 8-cycle
// LDS minimum. Swizzle applied uniformly: ldf/stt/stmax16/stG/ldE.
// Structure unchanged from R12 (passing): 4 congr waves own 16-col strips,
// 4 builder waves, deferred amax, 2 barriers per site.
// Slots: 0=S, 1=S', 2-3=Gi, 4-7=Go, 8-11=U scratch (one per congr wave).
// ---------------------------------------------------------------------------

typedef __attribute__((ext_vector_type(8))) short bf16x8;
typedef __attribute__((ext_vector_type(4))) float f32x4;
typedef unsigned short US;

__device__ __forceinline__ US f2b(float f) {
    union { float f; unsigned u; } v; v.f = f;
    return (US)((v.u + 0x7FFFu + ((v.u >> 16) & 1u)) >> 16);
}
__device__ __forceinline__ float bf2f(US h) {
    union { unsigned u; float f; } v; v.u = ((unsigned)h) << 16; return v.f;
}

struct Frag { bf16x8 lo, hi; };

// fragment for 16 storage-rows starting row0, K=64 in 2 halves (swizzled)
__device__ __forceinline__ Frag ldf(const US* buf, int row0, int lane) {
    const int r = row0 + (lane & 15);
    const int o = ((lane >> 4) << 3) ^ (((r >> 3) & 1) << 3);
    const US* p = buf + r * LDM + o;
    Frag f; f.lo = *(const bf16x8*)p; f.hi = *(const bf16x8*)(p + 32); return f;
}
__device__ __forceinline__ f32x4 mm(const Frag& a, const Frag& b, f32x4 c) {
    c = __builtin_amdgcn_mfma_f32_16x16x32_bf16(a.lo, b.lo, c, 0, 0, 0);
    c = __builtin_amdgcn_mfma_f32_16x16x32_bf16(a.hi, b.hi, c, 0, 0, 0);
    return c;
}
// write 16x16 C-tile transposed-bf16 (C layout: col=lane&15, row=quad*4+reg)
__device__ __forceinline__ void stt(US* dst, f32x4 d, float s,
                                    int col0, int row0, int lane) {
    ushort4 wv;
    wv.x = f2b(d.x * s); wv.y = f2b(d.y * s);
    wv.z = f2b(d.z * s); wv.w = f2b(d.w * s);
    const int r = col0 + (lane & 15);
    const int e = (row0 + ((lane >> 4) << 2)) ^ (((r >> 3) & 1) << 3);
    *(ushort4*)(dst + r * LDM + e) = wv;
}
// builder store: logical 8-elem chunk `chunk` of storage row srow
__device__ __forceinline__ void stG(US* slot, int srow, int chunk, bf16x8 v) {
    const int o = (chunk << 3) ^ (((srow >> 3) & 1) << 3);
    *(bf16x8*)(slot + srow * LDM + o) = v;
}
// scalar element read (storage row srow, element e)
__device__ __forceinline__ float ldE(const US* slot, int srow, int e) {
    return bf2f(slot[srow * LDM + (e ^ (((srow >> 3) & 1) << 3))]);
}
// scalar element write
__device__ __forceinline__ void stE(US* slot, int srow, int e, float v) {
    slot[srow * LDM + (e ^ (((srow >> 3) & 1) << 3))] = f2b(v);
}

// Pipelined congruence for strip CT: acc = sum_g G_g^T S G_g (cols CT*16..+16)
template<int NG, int CT>
__device__ __forceinline__ void congr16(US* sm, int sSlot, int gSlot, US* Uw,
                                        f32x4 acc[4], int lane) {
    const int C0 = CT * 16;
    const US* S = sm + sSlot * SLOTS;
    Frag aS[4];
#pragma unroll
    for (int rt = 0; rt < 4; ++rt) aS[rt] = ldf(S, rt * 16, lane);
    Frag bG[NG];
#pragma unroll
    for (int g = 0; g < NG; ++g) bG[g] = ldf(sm + (gSlot + g) * SLOTS, C0, lane);
    // stage1 for ALL gens: U_g[:, strip] = S * G_g
#pragma unroll
    for (int g = 0; g < NG; ++g) {
        US* Ug = Uw + g * (16 * LDM);
#pragma unroll
        for (int rt = 0; rt < 4; ++rt) {
            f32x4 d = {0.f, 0.f, 0.f, 0.f};
            d = mm(aS[rt], bG[g], d);
            stt(Ug, d, 1.f, 0, rt * 16, lane);
        }
    }
#pragma unroll
    for (int rt = 0; rt < 4; ++rt) acc[rt] = (f32x4){0.f, 0.f, 0.f, 0.f};
    // stage2: acc += G_g^T U_g  (bG reused as the rt==CT A-frag)
#pragma unroll
    for (int g = 0; g < NG; ++g) {
        const US* G = sm + (gSlot + g) * SLOTS;
        Frag bU = ldf(Uw + g * (16 * LDM), 0, lane);
#pragma unroll
        for (int rt = 0; rt < 4; ++rt) {
            if (rt == CT) {
                acc[rt] = mm(bG[g], bU, acc[rt]);
            } else {
                Frag ga = ldf(G, rt * 16, lane);
                acc[rt] = mm(ga, bU, acc[rt]);
            }
        }
    }
}

template<int NG>
__device__ __forceinline__ void congrD(US* sm, int sSlot, int gSlot, US* Uw,
                                       f32x4 acc[4], int ct, int lane) {
    switch (ct) {
        case 0:  congr16<NG, 0>(sm, sSlot, gSlot, Uw, acc, lane); break;
        case 1:  congr16<NG, 1>(sm, sSlot, gSlot, Uw, acc, lane); break;
        case 2:  congr16<NG, 2>(sm, sSlot, gSlot, Uw, acc, lane); break;
        default: congr16<NG, 3>(sm, sSlot, gSlot, Uw, acc, lane); break;
    }
}

__device__ __forceinline__ void stacc16(US* Sb, const f32x4 acc[4], float s,
                                        int C0, int lane) {
#pragma unroll
    for (int rt = 0; rt < 4; ++rt) stt(Sb, acc[rt], s, C0, rt * 16, lane);
}

// scaled store + wave-max of stored values (swizzled)
__device__ __forceinline__ float stmax16(US* Sb, const f32x4 acc[4], float s,
                                         int C0, int lane) {
    float m = 0.f;
    const int r = C0 + (lane & 15);
    const int q4 = (lane >> 4) << 2;
    const int bx = ((r >> 3) & 1) << 3;
#pragma unroll
    for (int rt = 0; rt < 4; ++rt) {
        float vx = acc[rt].x * s, vy = acc[rt].y * s;
        float vz = acc[rt].z * s, vw = acc[rt].w * s;
        m = fmaxf(m, fmaxf(fmaxf(fabsf(vx), fabsf(vy)),
                           fmaxf(fabsf(vz), fabsf(vw))));
        ushort4 wv; wv.x = f2b(vx); wv.y = f2b(vy); wv.z = f2b(vz); wv.w = f2b(vw);
        *(ushort4*)(Sb + r * LDM + ((rt * 16 + q4) ^ bx)) = wv;
    }
#pragma unroll
    for (int off = 32; off; off >>= 1) m = fmaxf(m, __shfl_down(m, off, 64));
    return m;
}

__global__ __launch_bounds__(TPB)
void mps_proj_kernel(const float* __restrict__ x,
                     const float* __restrict__ mi,
                     const float* __restrict__ mo,
                     float* __restrict__ out) {
    __shared__ __align__(16) US smem[12 * SLOTS];
#define SL(i) (smem + (i) * SLOTS)
    __shared__ float fsA[256];
    __shared__ float fsp[8];
    __shared__ float fsrA[2][4];
    __shared__ float fsrB[2][4];
    __shared__ float fsv[128];

    const int tid  = threadIdx.x;
    const int lane = tid & 63;
    const int w    = tid >> 6;
    const int C0   = (w & 3) * 16;                 // congr strip (w<4)
    US* const Uw   = smem + (8 + (w & 3)) * SLOTS; // per-congr-wave U scratch

    const float2* mi2 = (const float2*)mi;
    const float4* mo4 = (const float4*)mo;

    float logsum = 0.f;
    f32x4 acc[4];

    if (blockIdx.x < 128) {
        // =================== per-batch MPS scan, b = blockIdx.x ==================
        const int b = blockIdx.x;
        const float xa = x[b * 2 + 0], xb = x[b * 2 + 1];
        if (tid < 64) {
            float4 v = mo4[tid];
            fsA[tid * 2 + 0] = xa * v.x + xb * v.z;
            fsA[tid * 2 + 1] = xa * v.y + xb * v.w;
        }
        __syncthreads();
        float vals[8]; float mloc = 0.f;
#pragma unroll
        for (int j = 0; j < 8; ++j) {
            int pos = tid + j * TPB; int u = pos >> 6, d = pos & 63;
            float s = fsA[u * 2] * fsA[d * 2] + fsA[u * 2 + 1] * fsA[d * 2 + 1];
            vals[j] = s; mloc = fmaxf(mloc, fabsf(s));
        }
#pragma unroll
        for (int off = 32; off; off >>= 1) mloc = fmaxf(mloc, __shfl_down(mloc, off, 64));
        if (lane == 0) fsp[w] = mloc;
        __syncthreads();
        float amax = fsp[0];
#pragma unroll
        for (int i = 1; i < 8; ++i) amax = fmaxf(amax, fsp[i]);
        logsum = logf(amax);
        {
            float inv = 1.f / amax;
#pragma unroll
            for (int j = 0; j < 8; ++j) {
                int pos = tid + j * TPB;
                stE(SL(0), pos >> 6, pos & 63, vals[j] * inv);
            }
        }
        if (w >= 4) {   // build Gi = Ain(0) into slot 2
            const int j = w - 4;
            const float x1a = x[256 + b * 2 + 0], x1b = x[256 + b * 2 + 1];
            bf16x8 g0, g1;
#pragma unroll
            for (int t = 0; t < 8; ++t) {
                float2 m0 = mi2[(16 * j + t) * 64 + lane];
                float2 m1 = mi2[(16 * j + 8 + t) * 64 + lane];
                g0[t] = (short)f2b(x1a * m0.x + x1b * m0.y);
                g1[t] = (short)f2b(x1a * m1.x + x1b * m1.y);
            }
            stG(SL(2), lane, 2 * j, g0);
            stG(SL(2), lane, 2 * j + 1, g1);
        }
        if (tid < 4) fsrB[1][tid] = 1.f;   // deferred-scale init (S normalized)
        __syncthreads();

        for (int k = 0; k < 63; ++k) {
            // Phase A: Smid(slot1) = Ain^T S Ain, UNSCALED || build X0,X1(k+1)
            if (w < 4) {
                congrD<1>(smem, 0, 2, Uw, acc, w & 3, lane);
                stacc16(SL(1), acc, 1.f, C0, lane);
            } else {
                const int j = w - 4;
                const float x0a = x[(2 * k + 2) * 256 + b * 2 + 0];
                const float x0b = x[(2 * k + 2) * 256 + b * 2 + 1];
                const float4* so = mo4 + (k + 1) * 4096;
                bf16x8 a0, a1, c0, c1;
#pragma unroll
                for (int t = 0; t < 8; ++t) {
                    float4 m0 = so[(16 * j + t) * 64 + lane];
                    float4 m1 = so[(16 * j + 8 + t) * 64 + lane];
                    a0[t] = (short)f2b(x0a * m0.x + x0b * m0.z);
                    c0[t] = (short)f2b(x0a * m0.y + x0b * m0.w);
                    a1[t] = (short)f2b(x0a * m1.x + x0b * m1.z);
                    c1[t] = (short)f2b(x0a * m1.y + x0b * m1.w);
                }
                stG(SL(4), lane, 2 * j, a0);
                stG(SL(4), lane, 2 * j + 1, a1);
                stG(SL(5), lane, 2 * j, c0);
                stG(SL(5), lane, 2 * j + 1, c1);
            }
            __syncthreads();
            // Phase B: S(slot0) = (sum_t X_t^T Smid X_t)/a_prev || build Ain(k+1)
            if (w < 4) {
                float a = fmaxf(fmaxf(fsrB[(k + 1) & 1][0], fsrB[(k + 1) & 1][1]),
                                fmaxf(fsrB[(k + 1) & 1][2], fsrB[(k + 1) & 1][3]));
                logsum += logf(a);
                congrD<2>(smem, 1, 4, Uw, acc, w & 3, lane);
                float m = stmax16(SL(0), acc, 1.f / a, C0, lane);
                if (lane == 0) fsrB[k & 1][w] = m;
            } else {
                const int j = w - 4;
                const float x1a = x[(2 * k + 3) * 256 + b * 2 + 0];
                const float x1b = x[(2 * k + 3) * 256 + b * 2 + 1];
                const float2* si = mi2 + (k + 1) * 4096;
                bf16x8 g0, g1;
#pragma unroll
                for (int t = 0; t < 8; ++t) {
                    float2 m0 = si[(16 * j + t) * 64 + lane];
                    float2 m1 = si[(16 * j + 8 + t) * 64 + lane];
                    g0[t] = (short)f2b(x1a * m0.x + x1b * m0.y);
                    g1[t] = (short)f2b(x1a * m1.x + x1b * m1.y);
                }
                stG(SL(2), lane, 2 * j, g0);
                stG(SL(2), lane, 2 * j + 1, g1);
            }
            __syncthreads();
        }

        // ---- last site: out[b] = logsum + log(sum_i v_i^T S v_i) ----
        {
            const float x0a = x[128 * 256 + b * 2 + 0];
            const float x0b = x[128 * 256 + b * 2 + 1];
            if (tid < 64) {
                float4 v = mo4[64 * 4096 + tid * 64];
                fsA[tid * 2 + 0] = x0a * v.x + x0b * v.z;
                fsA[tid * 2 + 1] = x0a * v.y + x0b * v.w;
            }
            __syncthreads();
            if (tid < 128) {        // v[l][i] = sum_r Ain63[l][r] w[r][i]
                int dd = tid >> 1, ii = tid & 1;
                float s = 0.f;
                for (int r = 0; r < 64; ++r)
                    s += ldE(SL(2), r, dd) * fsA[r * 2 + ii];
                fsv[tid] = s;
            }
            __syncthreads();
            float part = 0.f;
#pragma unroll
            for (int j = 0; j < 8; ++j) {
                int pos = tid + j * TPB; int dd = pos >> 6, uu = pos & 63;
                part += ldE(SL(0), dd, uu) *
                        (fsv[dd * 2] * fsv[uu * 2] + fsv[dd * 2 + 1] * fsv[uu * 2 + 1]);
            }
#pragma unroll
            for (int off = 32; off; off >>= 1) part += __shfl_down(part, off, 64);
            if (lane == 0) fsp[w] = part;
            __syncthreads();
            if (tid == 0) {
                float t = 0.f;
#pragma unroll
                for (int i = 0; i < 8; ++i) t += fsp[i];
                out[b] = logsum + logf(t);
            }
        }
    } else {
        // ============================ lnrm scalar chain ==========================
        if (tid < 64) {
            float4 v = mo4[tid];
            fsA[tid * 4 + 0] = v.x; fsA[tid * 4 + 1] = v.y;
            fsA[tid * 4 + 2] = v.z; fsA[tid * 4 + 3] = v.w;
        }
        __syncthreads();
        float vals[8]; float mloc = 0.f;
#pragma unroll
        for (int j = 0; j < 8; ++j) {
            int pos = tid + j * TPB; int kk = pos >> 6, ll = pos & 63;
            float s = fsA[kk*4+0]*fsA[ll*4+0] + fsA[kk*4+1]*fsA[ll*4+1] +
                      fsA[kk*4+2]*fsA[ll*4+2] + fsA[kk*4+3]*fsA[ll*4+3];
            vals[j] = s; mloc = fmaxf(mloc, fabsf(s));
        }
#pragma unroll
        for (int off = 32; off; off >>= 1) mloc = fmaxf(mloc, __shfl_down(mloc, off, 64));
        if (lane == 0) fsp[w] = mloc;
        __syncthreads();
        float amax = fsp[0];
#pragma unroll
        for (int i = 1; i < 8; ++i) amax = fmaxf(amax, fsp[i]);
        logsum = logf(amax);
        {
            float inv = 1.f / amax;
#pragma unroll
            for (int j = 0; j < 8; ++j) {
                int pos = tid + j * TPB;
                stE(SL(0), pos >> 6, pos & 63, vals[j] * inv);
            }
        }
        if (w >= 4) {   // build Gi0,Gi1 from mi[0] -> slots 2,3
            const int j = w - 4;
            bf16x8 g00, g01, g10, g11;
#pragma unroll
            for (int t = 0; t < 8; ++t) {
                float2 m0 = mi2[(16 * j + t) * 64 + lane];
                float2 m1 = mi2[(16 * j + 8 + t) * 64 + lane];
                g00[t] = (short)f2b(m0.x); g10[t] = (short)f2b(m0.y);
                g01[t] = (short)f2b(m1.x); g11[t] = (short)f2b(m1.y);
            }
            stG(SL(2), lane, 2 * j, g00);
            stG(SL(2), lane, 2 * j + 1, g01);
            stG(SL(3), lane, 2 * j, g10);
            stG(SL(3), lane, 2 * j + 1, g11);
        }
        if (tid < 4) fsrB[1][tid] = 1.f;
        __syncthreads();

        for (int n = 0; n < 64; ++n) {
            // Phase A: S'(slot1) = (sum_t Mi_t^T S Mi_t)/aB || build Go from mo[n+1]
            if (w < 4) {
                float aB = fmaxf(fmaxf(fsrB[(n + 1) & 1][0], fsrB[(n + 1) & 1][1]),
                                 fmaxf(fsrB[(n + 1) & 1][2], fsrB[(n + 1) & 1][3]));
                logsum += logf(aB);
                congrD<2>(smem, 0, 2, Uw, acc, w & 3, lane);
                float m = stmax16(SL(1), acc, 1.f / aB, C0, lane);
                if (lane == 0) fsrA[n & 1][w] = m;
            } else {
                const int j = w - 4;
                const float4* so = mo4 + (n + 1) * 4096;
                bf16x8 g[4][2];
#pragma unroll
                for (int t = 0; t < 8; ++t) {
                    float4 m0 = so[(16 * j + t) * 64 + lane];
                    float4 m1 = so[(16 * j + 8 + t) * 64 + lane];
                    g[0][0][t] = (short)f2b(m0.x); g[1][0][t] = (short)f2b(m0.y);
                    g[2][0][t] = (short)f2b(m0.z); g[3][0][t] = (short)f2b(m0.w);
                    g[0][1][t] = (short)f2b(m1.x); g[1][1][t] = (short)f2b(m1.y);
                    g[2][1][t] = (short)f2b(m1.z); g[3][1][t] = (short)f2b(m1.w);
                }
#pragma unroll
                for (int c = 0; c < 4; ++c) {
                    stG(SL(4 + c), lane, 2 * j, g[c][0]);
                    stG(SL(4 + c), lane, 2 * j + 1, g[c][1]);
                }
            }
            __syncthreads();
            // Phase B: S(slot0) = (sum_c Mo_c^T S' Mo_c)/aA || build Gi(n+1)
            if (w < 4) {
                float aA = fmaxf(fmaxf(fsrA[n & 1][0], fsrA[n & 1][1]),
                                 fmaxf(fsrA[n & 1][2], fsrA[n & 1][3]));
                logsum += logf(aA);
                congrD<4>(smem, 1, 4, Uw, acc, w & 3, lane);
                float m = stmax16(SL(0), acc, 1.f / aA, C0, lane);
                if (lane == 0) fsrB[n & 1][w] = m;
            } else if (n < 63) {
                const int j = w - 4;
                const float2* si = mi2 + (n + 1) * 4096;
                bf16x8 g00, g01, g10, g11;
#pragma unroll
                for (int t = 0; t < 8; ++t) {
                    float2 m0 = si[(16 * j + t) * 64 + lane];
                    float2 m1 = si[(16 * j + 8 + t) * 64 + lane];
                    g00[t] = (short)f2b(m0.x); g10[t] = (short)f2b(m0.y);
                    g01[t] = (short)f2b(m1.x); g11[t] = (short)f2b(m1.y);
                }
                stG(SL(2), lane, 2 * j, g00);
                stG(SL(2), lane, 2 * j + 1, g01);
                stG(SL(3), lane, 2 * j, g10);
                stG(SL(3), lane, 2 * j + 1, g11);
            }
            __syncthreads();
        }
        if (tid == 0) out[128] = logsum + logf(ldE(SL(0), 0, 0));
    }
#undef SL
}

extern "C" void kernel_launch(void* const* d_in, const int* in_sizes, int n_in,
                              void* d_out, int out_size, void* d_ws, size_t ws_size,
                              hipStream_t stream) {
    (void)in_sizes; (void)n_in; (void)d_ws; (void)ws_size; (void)out_size;
    const float* x  = (const float*)d_in[0];
    const float* mi = (const float*)d_in[1];
    const float* mo = (const float*)d_in[2];
    float* out = (float*)d_out;
    hipLaunchKernelGGL(mps_proj_kernel, dim3(129), dim3(TPB), 0, stream,
                       x, mi, mo, out);
}